// Round 1
// baseline (98.754 us; speedup 1.0000x reference)
//
#include <hip/hip_runtime.h>
#include <stdint.h>
#include <stddef.h>

// Problem: out[b][o] = sum_{i,g} spline(x[b][i])[g] * coef[o][i][g]
//   x: (4096, 1024) f32; coef: (1024, 1024, 8) f32; out: (4096, 1024) f32
// == GEMM: A (4096 x 8192) * B^T (1024 x 8192), K = i*8+g.
//
// Both operands pre-shuffled into 16x16x32-MFMA fragment images (prep_kernel)
// so the GEMM stages whole 1KB fragments via global_load_lds and every
// ds_read is base+lane*16 (conflict-free). 256x256 tile, 8 waves, split-K=4.
// R1 change: ds_reads are issued MID-MFMA-cluster (between the two kk-halves,
// WAR-safe) and global_load_lds stages at window START, so LDS-unit busy and
// VMEM issue overlap matrix-pipe busy instead of serializing after it.
// Counted vmcnt(4), setprio around each interleaved cluster.
// Split s=0 writes C f32; s>0 write bf16 partials; reduce kernel sums.

#define BATCH 4096
#define IN    1024
#define OUTN  1024
#define KDIM  (IN * 8)     // 8192
#define NTT   (KDIM / 64)  // 128 K-tiles of BK=64

typedef __attribute__((ext_vector_type(8)))  short          short8;
typedef __attribute__((ext_vector_type(8)))  unsigned short ushort8;
typedef __attribute__((ext_vector_type(4)))  float          f32x4;

// ---------- helpers ----------

__device__ __forceinline__ constexpr float Cf(int i) {
    constexpr double end  = 1.0 + 2.0 * 4.0 / 7.0;        // 1 + 8/7
    constexpr double step = (end - (-1.0)) / 11.0;
    return (float)(-1.0 + (double)i * step);
}

__device__ __forceinline__ unsigned short f2bf(float f) {
    unsigned int u = __builtin_bit_cast(unsigned int, f);
    u += 0x7fffu + ((u >> 16) & 1u);      // round-to-nearest-even
    return (unsigned short)(u >> 16);
}

__device__ __forceinline__ float bf2f(unsigned short u) {
    unsigned int v = (unsigned int)u << 16;
    return __builtin_bit_cast(float, v);
}

__device__ __forceinline__ ushort8 spline8(float xt) {
    float v[11];
#pragma unroll
    for (int j = 0; j < 11; ++j)
        v[j] = (xt >= Cf(j) && xt < Cf(j + 1)) ? 1.0f : 0.0f;
#pragma unroll
    for (int k = 1; k <= 3; ++k) {
#pragma unroll
        for (int j = 0; j < 11 - k; ++j) {
            float left  = (xt - Cf(j))         * (1.0f / (Cf(j + k)     - Cf(j)));
            float right = (Cf(j + k + 1) - xt) * (1.0f / (Cf(j + k + 1) - Cf(j + 1)));
            v[j] = left * v[j] + right * v[j + 1];
        }
    }
    ushort8 r;
#pragma unroll
    for (int g = 0; g < 8; ++g) r[g] = f2bf(v[g]);
    return r;
}

typedef const unsigned int __attribute__((address_space(1))) gu32;
typedef unsigned int       __attribute__((address_space(3))) lu32;

__device__ __forceinline__ void gload_lds16(const void* g, void* l) {
    __builtin_amdgcn_global_load_lds((gu32*)g, (lu32*)l, 16, 0, 0);
}

// ---------- kernel 1: fused prep -> A_shuf / B_shuf fragment images ----------
//
// 16x16x32 frag map: row = lane&15, k = kb*32 + (lane>>4)*8 + e.
// Image (ushort8 units): [rg=row>>4][kb=k>>5][lane][e].
// Element (row, i, g): kb = i>>2, lane = (i&3)*16 + (row&15), e = g.

__global__ void prep_kernel(const float* __restrict__ x, const float* __restrict__ coef,
                            unsigned short* __restrict__ A, unsigned short* __restrict__ B) {
    const int t = threadIdx.x;
    int blk = blockIdx.x;
    if (blk < 4096) {
        // basis: 256 bb x 16 bi blocks; row = b
        const int bb = blk >> 4, bi = blk & 15;
        const int b  = bb * 16 + (t & 15);
        const int i0 = bi * 64 + (t >> 4) * 4;
        f32x4 xv = *reinterpret_cast<const f32x4*>(&x[(size_t)b * IN + i0]);
        ushort8 r[4];
#pragma unroll
        for (int j = 0; j < 4; ++j) r[j] = spline8(tanhf(xv[j]));
        ushort8* out = reinterpret_cast<ushort8*>(A)
                     + ((size_t)(bb * 256 + bi * 16 + (t >> 4)) * 64) + (t & 15);
        out[0]  = r[0];
        out[16] = r[1];
        out[32] = r[2];
        out[48] = r[3];
    } else {
        // coef cvt: 64 ob x 16 ib blocks; row = o
        blk -= 4096;
        const int ob = blk >> 4, ib = blk & 15;
        const int oo = ob * 16 + (t & 15);
        const int i0 = ib * 64 + (t >> 4) * 4;
        const f32x4* cin = reinterpret_cast<const f32x4*>(coef);
        ushort8 r[4];
#pragma unroll
        for (int j = 0; j < 4; ++j) {
            f32x4 v0 = cin[((size_t)oo * IN + i0 + j) * 2];
            f32x4 v1 = cin[((size_t)oo * IN + i0 + j) * 2 + 1];
#pragma unroll
            for (int g = 0; g < 4; ++g) { r[j][g] = f2bf(v0[g]); r[j][4 + g] = f2bf(v1[g]); }
        }
        ushort8* out = reinterpret_cast<ushort8*>(B)
                     + ((size_t)(ob * 256 + ib * 16 + (t >> 4)) * 64) + (t & 15);
        out[0]  = r[0];
        out[16] = r[1];
        out[32] = r[2];
        out[48] = r[3];
    }
}

// ---------- kernel 2: 256x256 bf16 GEMM, pipelined 4 windows/K-tile ----------
//
// 8 waves (wm=w>>2, wn=w&3), per-wave output 128x64 interleaved H/V.
// Windows per tile t (buf c = t%2, n = other). Every window: BAR; stages
// issue FIRST (VMEM in flight early); then the 16-MFMA cluster split into
// kk-halves with the window's ds_reads issued BETWEEN the halves so the LDS
// unit drains while the matrix pipe is busy:
//  W1: BAR; stage B1,A1(t+1)->n; [8 MFMA kk0 | read bv1(t) | 8 MFMA kk1]
//  W2: BAR; stage B0(t+2)->c;    [8 MFMA kk0 | read aF[*][0]<-A1(t) | 8 MFMA kk1 | read aF[*][1]]
//  W3: BAR; stage A0(t+2)->c;    [16 MFMA]; vmcnt(4)
//  W4: BAR(publish t+1);         [8 MFMA kk0 | read aF[*][0],bv0(t+1)<-n | 8 MFMA kk1 | read aF[*][1]]
// WAR safety: each kk-half fully consumes aF[*][kk] before the trailing read
// overwrites it; bv reads never alias the half's B operand.
// Stage-safety: every LDS slot's last read retired (lgkm-consumed by an MFMA
// in an earlier window) >=1 full window before its re-stage ISSUE.
// vmcnt: 12 outstanding at W3 -> vmcnt(4) retires tile t+1's four halves,
// leaves B0/A0(t+2).

#define LSA0 (&Ls[0][0])
#define LSB0 (&Ls[0][16384])
#define LSA1 (&Ls[1][0])
#define LSB1 (&Ls[1][16384])

template<int NSPLIT>
__global__ __launch_bounds__(512, 2) void gemm_bt(
        const unsigned short* __restrict__ Ashuf,  // [256 rg][256 kb][64][8]
        const unsigned short* __restrict__ Bshuf,  // [64 cg][256 kb][64][8]
        float* __restrict__ C,                     // [4096][1024]
        unsigned short* __restrict__ P) {          // bf16 partials (splits 1..)
    constexpr int NT2 = NTT / NSPLIT;              // K-tiles per block
    static_assert((NT2 & 1) == 0, "loop assumes even NT2");
    __shared__ unsigned short Ls[2][32768];        // 128 KiB

    const int tid  = threadIdx.x;
    const int w    = tid >> 6;                     // 0..7
    const int lane = tid & 63;
    const int wm   = w >> 2, wn = w & 3;
    const int kkw  = w & 1, wh = w >> 1;           // staging roles
    const int lane8 = lane * 8;

    const int bid  = blockIdx.x;
    const int s    = bid & (NSPLIT - 1);
    const int tile = bid / NSPLIT;                 // 0..63
    const int mb16 = (tile >> 2) * 16;             // A rg base
    const int nb16 = (tile & 3) * 16;              // B cg base
    const int T0   = s * NT2;
    const int brow = mb16 * 16, bcol = nb16 * 16;

#define STAGE_OP(BASE, NB16, H, T, LS) do {                                   \
        size_t _kq = ((size_t)(2 * (T0 + (T)) + kkw)) * 512 + lane8;          \
        const unsigned short* _g = (BASE) + ((size_t)((NB16) + (H)*8 + wh) << 17) + _kq; \
        unsigned short* _l = (LS) + (((H)*16 + w) << 9);                      \
        gload_lds16(_g, _l);                                                  \
        gload_lds16(_g + ((size_t)4 << 17), _l + (8 << 9));                   \
    } while (0)
#define STAGE_A(H, T, LS) STAGE_OP(Ashuf, mb16, H, T, LS)
#define STAGE_B(H, T, LS) STAGE_OP(Bshuf, nb16, H, T, LS)

#define LDA_F(DST, H, LS) do {                                                \
        _Pragma("unroll")                                                     \
        for (int mf = 0; mf < 4; ++mf)                                        \
            _Pragma("unroll")                                                 \
            for (int kk = 0; kk < 2; ++kk)                                    \
                DST[mf][kk] = *reinterpret_cast<const short8*>(               \
                    (LS) + (((((H)*8 + wm*4 + mf) * 2) + kk) << 9) + lane8);  \
    } while (0)
#define LDA_H(DST, H, LS, KK) do {                                            \
        _Pragma("unroll")                                                     \
        for (int mf = 0; mf < 4; ++mf)                                        \
            DST[mf][KK] = *reinterpret_cast<const short8*>(                   \
                (LS) + (((((H)*8 + wm*4 + mf) * 2) + (KK)) << 9) + lane8);    \
    } while (0)
#define LDB_F(DST, V, LS) do {                                                \
        _Pragma("unroll")                                                     \
        for (int nf = 0; nf < 2; ++nf)                                        \
            _Pragma("unroll")                                                 \
            for (int kk = 0; kk < 2; ++kk)                                    \
                DST[nf][kk] = *reinterpret_cast<const short8*>(               \
                    (LS) + (((((V)*8 + wn*2 + nf) * 2) + kk) << 9) + lane8);  \
    } while (0)

    f32x4 acc[8][4] = {};                          // [H*4+mf][V*2+nf]
    short8 aF[4][2], bv0[2][2], bv1[2][2];

    // one kk-half of a quadrant: 8 independent MFMAs
#define MFMA_H(H, V, KK, AF, BV) do {                                         \
        _Pragma("unroll")                                                     \
        for (int mf = 0; mf < 4; ++mf)                                        \
            _Pragma("unroll")                                                 \
            for (int nf = 0; nf < 2; ++nf)                                    \
                acc[(H)*4 + mf][(V)*2 + nf] =                                 \
                    __builtin_amdgcn_mfma_f32_16x16x32_bf16(                  \
                        AF[mf][KK], BV[nf][KK],                               \
                        acc[(H)*4 + mf][(V)*2 + nf], 0, 0, 0);                \
    } while (0)

    // Pipelined tile: stages first, reads interleaved mid-cluster.
#define TILE(T, LAC, LBC, LAN, LBN, S1F, S23F, RN, VC) do {                   \
        __builtin_amdgcn_s_barrier();                                         \
        if (S1F) { STAGE_B(1, (T) + 1, LBN); STAGE_A(1, (T) + 1, LAN); }      \
        __builtin_amdgcn_s_setprio(1);                                        \
        MFMA_H(0, 0, 0, aF, bv0);                                             \
        LDB_F(bv1, 1, LBC);                                                   \
        MFMA_H(0, 0, 1, aF, bv0);                                             \
        __builtin_amdgcn_s_setprio(0);                                        \
        __builtin_amdgcn_s_barrier();                                         \
        if (S23F) STAGE_B(0, (T) + 2, LBC);                                   \
        __builtin_amdgcn_s_setprio(1);                                        \
        MFMA_H(0, 1, 0, aF, bv1);                                             \
        LDA_H(aF, 1, LAC, 0);                                                 \
        MFMA_H(0, 1, 1, aF, bv1);                                             \
        LDA_H(aF, 1, LAC, 1);                                                 \
        __builtin_amdgcn_s_setprio(0);                                        \
        __builtin_amdgcn_s_barrier();                                         \
        if (S23F) STAGE_A(0, (T) + 2, LAC);                                   \
        __builtin_amdgcn_s_setprio(1);                                        \
        MFMA_H(1, 0, 0, aF, bv0);                                             \
        MFMA_H(1, 0, 1, aF, bv0);                                             \
        __builtin_amdgcn_s_setprio(0);                                        \
        asm volatile("s_waitcnt vmcnt(" VC ")" ::: "memory");                 \
        __builtin_amdgcn_s_barrier();                                         \
        __builtin_amdgcn_s_setprio(1);                                        \
        MFMA_H(1, 1, 0, aF, bv1);                                             \
        if (RN) { LDA_H(aF, 0, LAN, 0); LDB_F(bv0, 0, LBN); }                 \
        MFMA_H(1, 1, 1, aF, bv1);                                             \
        if (RN) { LDA_H(aF, 0, LAN, 1); }                                     \
        __builtin_amdgcn_s_setprio(0);                                        \
    } while (0)

    // prologue: 12 gloads (tile0's 4 halves + tile1's B0/A0); publish tile 0;
    // pre-read tile0's A0/bv0 (the "W4(-1)" of the pipeline).
    STAGE_B(0, 0, LSB0); STAGE_A(0, 0, LSA0);
    STAGE_B(1, 0, LSB0); STAGE_A(1, 0, LSA0);
    STAGE_B(0, 1, LSB1); STAGE_A(0, 1, LSA1);
    asm volatile("s_waitcnt vmcnt(4)" ::: "memory");
    __builtin_amdgcn_s_barrier();
    LDA_F(aF, 0, LSA0); LDB_F(bv0, 0, LSB0);

#pragma unroll 1
    for (int t = 0; t + 2 <= NT2 - 2; t += 2) {
        TILE(t,     LSA0, LSB0, LSA1, LSB1, 1, 1, 1, "4");
        TILE(t + 1, LSA1, LSB1, LSA0, LSB0, 1, 1, 1, "4");
    }
    TILE(NT2 - 2, LSA0, LSB0, LSA1, LSB1, 1, 0, 1, "0");
    TILE(NT2 - 1, LSA1, LSB1, LSA0, LSB0, 0, 0, 0, "0");

    // epilogue: C/D layout col=lane&15, row=(lane>>4)*4+reg (m89-verified)
    // s==0 -> f32 to C; s>0 -> bf16 partial slab (reduce kernel sums).
    const int q4 = (lane >> 4) * 4, frow = lane & 15;
    if (NSPLIT == 1 || s == 0) {
#pragma unroll
        for (int H = 0; H < 2; ++H)
#pragma unroll
            for (int mf = 0; mf < 4; ++mf)
#pragma unroll
                for (int V = 0; V < 2; ++V)
#pragma unroll
                    for (int nf = 0; nf < 2; ++nf)
#pragma unroll
                        for (int r = 0; r < 4; ++r) {
                            int row = brow + H * 128 + wm * 64 + mf * 16 + q4 + r;
                            int col = bcol + V * 128 + wn * 32 + nf * 16 + frow;
                            C[(size_t)row * OUTN + col] = acc[H * 4 + mf][V * 2 + nf][r];
                        }
    } else {
        unsigned short* Pb = P + (size_t)(s - 1) * BATCH * OUTN;
#pragma unroll
        for (int H = 0; H < 2; ++H)
#pragma unroll
            for (int mf = 0; mf < 4; ++mf)
#pragma unroll
                for (int V = 0; V < 2; ++V)
#pragma unroll
                    for (int nf = 0; nf < 2; ++nf)
#pragma unroll
                        for (int r = 0; r < 4; ++r) {
                            int row = brow + H * 128 + wm * 64 + mf * 16 + q4 + r;
                            int col = bcol + V * 128 + wn * 32 + nf * 16 + frow;
                            Pb[(size_t)row * OUTN + col] = f2bf(acc[H * 4 + mf][V * 2 + nf][r]);
                        }
    }
}

// ---------- kernel 3: C += sum of np bf16 partials ----------

__global__ void reduce_kernel(float* __restrict__ C, const unsigned short* __restrict__ P,
                              int np) {
    int i = blockIdx.x * 256 + threadIdx.x;        // 524,288 threads x 8 f32
    size_t base = (size_t)i * 8;
    f32x4 c0 = *reinterpret_cast<f32x4*>(&C[base]);
    f32x4 c1 = *reinterpret_cast<f32x4*>(&C[base + 4]);
    for (int j = 0; j < np; ++j) {
        ushort8 p = *reinterpret_cast<const ushort8*>(&P[(size_t)j * BATCH * OUTN + base]);
#pragma unroll
        for (int e = 0; e < 4; ++e) c0[e] += bf2f(p[e]);
#pragma unroll
        for (int e = 0; e < 4; ++e) c1[e] += bf2f(p[4 + e]);
    }
    *reinterpret_cast<f32x4*>(&C[base])     = c0;
    *reinterpret_cast<f32x4*>(&C[base + 4]) = c1;
}

// ---------- launch ----------

extern "C" void kernel_launch(void* const* d_in, const int* in_sizes, int n_in,
                              void* d_out, int out_size, void* d_ws, size_t ws_size,
                              hipStream_t stream) {
    const float* x    = (const float*)d_in[0];
    const float* coef = (const float*)d_in[1];
    float* out = (float*)d_out;

    // ws: [A_shuf 64 MiB][B_shuf 16 MiB][bf16 partials 8 MiB x (NSPLIT-1)]
    unsigned short* ashuf = (unsigned short*)d_ws;
    unsigned short* bshuf = ashuf + (size_t)BATCH * KDIM;
    unsigned short* part  = bshuf + (size_t)OUTN * KDIM;
    const size_t base = (size_t)BATCH * KDIM * 2 + (size_t)OUTN * KDIM * 2;  // 80 MiB
    const size_t slab = (size_t)BATCH * OUTN * 2;                            // 8 MiB

    prep_kernel<<<5120, 256, 0, stream>>>(x, coef, ashuf, bshuf);

    if (ws_size >= base + 3 * slab) {
        gemm_bt<4><<<256, 512, 0, stream>>>(ashuf, bshuf, out, part);
        reduce_kernel<<<2048, 256, 0, stream>>>(out, part, 3);
    } else if (ws_size >= base + slab) {
        gemm_bt<2><<<128, 512, 0, stream>>>(ashuf, bshuf, out, part);
        reduce_kernel<<<2048, 256, 0, stream>>>(out, part, 1);
    } else {
        gemm_bt<1><<<64, 512, 0, stream>>>(ashuf, bshuf, out, nullptr);
    }
}